// Round 8
// baseline (518.027 us; speedup 1.0000x reference)
//
#include <hip/hip_runtime.h>

using u16 = unsigned short;
using u32 = unsigned int;
using u64 = unsigned long long;

#define NPTS   16384
#define NPER   8192
#define KNN    16
#define NKROWS (NPTS*KNN)
#define HD     128
#define CAP    208   // per-wave candidate buffer slots
#define NSLOT  16    // fp64 stats partial slots
#define NREG   10    // stats regions: 5 stages x 2 layers

typedef _Float16 half8 __attribute__((ext_vector_type(8)));
typedef float    floatx4 __attribute__((ext_vector_type(4)));
typedef short          s16x2 __attribute__((ext_vector_type(2)));
typedef unsigned short u16x2 __attribute__((ext_vector_type(2)));
typedef _Float16       h2v   __attribute__((ext_vector_type(2)));

__device__ __forceinline__ u16  f2h(float f){ _Float16 h=(_Float16)f; return __builtin_bit_cast(u16,h); }
__device__ __forceinline__ float h2f(u16 u){ return (float)__builtin_bit_cast(_Float16,u); }
__device__ __forceinline__ u32 umin32(u32 a,u32 b){ return a<b?a:b; }
__device__ __forceinline__ u32 mbcnt64(u64 m){
    return __builtin_amdgcn_mbcnt_hi((u32)(m>>32), __builtin_amdgcn_mbcnt_lo((u32)m,0));
}
__device__ __forceinline__ h2v bch2(u32 x){ return __builtin_bit_cast(h2v,x); }
__device__ __forceinline__ u32 bcu(h2v x){ return __builtin_bit_cast(u32,x); }
// packed f16 relu: v_pk_max_f16 with a zero VGPR
__device__ __forceinline__ u32 pk_relu(u32 x){
    u32 r;
    asm("v_pk_max_f16 %0, %1, %2" : "=v"(r) : "v"(x), "v"(0u));
    return r;
}
// dx*dx + dy*dy + c via v_dot2_i32_i16 when available
__device__ __forceinline__ int sdot2_acc(s16x2 a, int c){
#if __has_builtin(__builtin_amdgcn_sdot2)
    return __builtin_amdgcn_sdot2(a, a, c, false);
#else
    return (int)a.x*(int)a.x + (int)a.y*(int)a.y + c;
#endif
}

// ---------------------------------------------------------------- prep
__global__ __launch_bounds__(256) void pack_coords(const int* __restrict__ coords, u32* __restrict__ pc){
    int i = blockIdx.x*256 + threadIdx.x;
    pc[i] = (u32)coords[3*i] | ((u32)coords[3*i+1]<<8) | ((u32)coords[3*i+2]<<16);
}

struct WPtrs { const float* p[8]; };
// wt[(t*2+l)*16384 + n*128 + k] = f16( W_t[l][k][n] )
__global__ __launch_bounds__(256) void prep_weights(WPtrs wp, u16* __restrict__ wt){
    int idx = blockIdx.x*256 + threadIdx.x;
    int t = idx>>15, rem = idx&32767;
    int l = rem>>14, e = rem&16383;
    int n = e>>7, k = e&127;
    wt[idx] = f2h(wp.p[t][l*16384 + k*128 + n]);
}

// ---------------------------------------------------------------- KNN v7: paired ballot common path
__global__ __launch_bounds__(512) void knn3(const u32* __restrict__ pc, int* __restrict__ idx_g,
                                            float* __restrict__ rel, u64* __restrict__ sM){
    __shared__ u32 sc[NPER];
    __shared__ u32 buf[8][CAP];
    __shared__ u64 red[9];
    int tid = threadIdx.x;
    int wave = tid>>6, lane = tid&63;
    int scene = blockIdx.x >> 10;                 // 1024 blocks per scene
    int q = (blockIdx.x & 1023)*8 + wave;

    const uint4* s4 = (const uint4*)(pc + scene*NPER);
#pragma unroll
    for (int i=0;i<4;i++) ((uint4*)sc)[tid + i*512] = s4[tid + i*512];
    if (tid<9) red[tid]=0;
    if (lane<16) buf[wave][lane]=0xFFFFFFFFu;
    __syncthreads();

    u32 qp = sc[q];
    int qx=(int)(qp&255), qy=(int)((qp>>8)&255), qz=(int)((qp>>16)&255);
    s16x2 qxy = __builtin_bit_cast(s16x2, __builtin_amdgcn_perm(0u, qp, 0x04010400u));
    s16x2 qzz = __builtin_bit_cast(s16x2, (qp>>16) * 0x00010001u);
    u32 thresh = 0xFFFFFFFFu;
    u32 td2 = thresh >> 13;
    u32 cnt = 16;                                  // buf[0..15] = current top-16 set

    auto tighten = [&](){
        u32 v0 = (lane      < (int)cnt) ? buf[wave][lane]      : 0xFFFFFFFFu;
        u32 v1 = (lane+64   < (int)cnt) ? buf[wave][lane+64]   : 0xFFFFFFFFu;
        u32 v2 = (lane+128  < (int)cnt) ? buf[wave][lane+128]  : 0xFFFFFFFFu;
        u32 v3 = (lane+192  < (int)cnt) ? buf[wave][lane+192]  : 0xFFFFFFFFu;
        u32 T = 0;
#pragma unroll
        for (int b=29;b>=0;b--){
            u32 Tt = T | (1u<<b);
            int c = __popcll(__ballot(v0<Tt)) + __popcll(__ballot(v1<Tt))
                  + __popcll(__ballot(v2<Tt)) + __popcll(__ballot(v3<Tt));
            if (c < 16) T = Tt;                    // wave-uniform (scalar) update
        }
        u64 m0=__ballot(v0<=T), m1=__ballot(v1<=T), m2=__ballot(v2<=T), m3=__ballot(v3<=T);
        u32 b0=(u32)__popcll(m0), b1=(u32)__popcll(m1), b2=(u32)__popcll(m2);
        if (v0<=T) buf[wave][mbcnt64(m0)]=v0;
        if (v1<=T) buf[wave][b0+mbcnt64(m1)]=v1;
        if (v2<=T) buf[wave][b0+b1+mbcnt64(m2)]=v2;
        if (v3<=T) buf[wave][b0+b1+b2+mbcnt64(m3)]=v3;
        cnt = 16;
        thresh = T;
        td2 = T >> 13;
    };

    int lane2 = lane*2;
    uint2 p2 = ((const uint2*)sc)[lane];
    for (int t=0;t<64;t++){
        uint2 cur = p2;
        if (t<63) p2 = ((const uint2*)sc)[(t+1)*64+lane];
        u32 pa = cur.x, pb = cur.y;
        s16x2 xy0 = __builtin_bit_cast(s16x2, __builtin_amdgcn_perm(0u, pa, 0x04010400u));
        s16x2 xy1 = __builtin_bit_cast(s16x2, __builtin_amdgcn_perm(0u, pb, 0x04010400u));
        u32 zzr = __builtin_amdgcn_perm(pb, pa, 0x00060002u) & 0x00FF00FFu;
        s16x2 dzz = __builtin_bit_cast(s16x2, zzr) - qzz;        // both dz in one pk_sub
        u16x2 dzu = __builtin_bit_cast(u16x2, dzz);
        u16x2 zsq = dzu*dzu;                                     // dz^2 <= 39601 exact mod 2^16
        u32 zb = __builtin_bit_cast(u32, zsq);
        s16x2 dxy0 = xy0 - qxy;
        s16x2 dxy1 = xy1 - qxy;
        u32 d2_0 = (u32)sdot2_acc(dxy0, (int)(zb & 0xFFFFu));
        u32 d2_1 = (u32)sdot2_acc(dxy1, (int)(zb >> 16));
        // single ballot on the pair-min in the common (no-hit) path
        u64 mp = __ballot(umin32(d2_0, d2_1) <= td2);
        if (mp){                                   // wave-uniform branch
            int base = t*128 + lane2;
            u64 m0 = __ballot(d2_0 <= td2);
            if (m0){
                if (d2_0 <= td2) buf[wave][cnt + mbcnt64(m0)] = (d2_0<<13) + (u32)base;
                cnt += (u32)__popcll(m0);
                if (cnt > CAP-64) tighten();
            }
            u64 m1 = __ballot(d2_1 <= td2);
            if (m1){
                if (d2_1 <= td2) buf[wave][cnt + mbcnt64(m1)] = (d2_1<<13) + (u32)(base+1);
                cnt += (u32)__popcll(m1);
                if (cnt > CAP-64) tighten();
            }
        }
    }
    tighten();                                     // exact top-16 (unsorted) in buf[0..15]

    // sort the 16 keys ascending: rank = #(keys smaller), keys unique
    {
        u32 myk = buf[wave][lane & 15];
        u32 rank = 0;
#pragma unroll
        for (int j=0;j<16;j++){ u32 o = buf[wave][j]; rank += (o < myk) ? 1u : 0u; }
        if (lane < 16) buf[wave][rank] = myk;
    }

    // epilogue: emit idx/rel + moment sums (for analytic d1-BN)
    int n = scene*NPER + q;
    u32 key = buf[wave][lane & 15];
    int dx=0,dy=0,dz=0;
    if (lane<16){
        int j = (int)(key & 8191u);
        idx_g[(size_t)n*KNN + lane] = scene*NPER + j;
        u32 p = sc[j];
        dx=(int)(p&255)-qx; dy=(int)((p>>8)&255)-qy; dz=(int)((p>>16)&255)-qz;
        size_t ro = ((size_t)n*KNN+lane)*3;
        rel[ro]=(float)dx; rel[ro+1]=(float)dy; rel[ro+2]=(float)dz;
    }
    int arr[9] = {dx,dy,dz, dx*dx,dy*dy,dz*dz, dx*dy,dx*dz,dy*dz};
#pragma unroll
    for (int o=32;o>=1;o>>=1)
#pragma unroll
        for (int j=0;j<9;j++) arr[j] += __shfl_xor(arr[j], o, 64);
    if (lane==0)
#pragma unroll
        for (int j=0;j<9;j++) atomicAdd(&red[j], (u64)(long long)arr[j]);
    __syncthreads();
    if (tid<9) atomicAdd(&sM[tid], red[tid]);
}

// analytic BN affine for the 3->H layer (runs once)
__global__ __launch_bounds__(256) void finalize_d1(const u64* __restrict__ sM, const float* __restrict__ W_d1,
        const float* __restrict__ b_d1, const float* __restrict__ g, const float* __restrict__ beta,
        float* __restrict__ A, float* __restrict__ C){
    int tid=threadIdx.x; int l=tid>>7, c=tid&127;
    double s0=(double)(long long)sM[0], s1=(double)(long long)sM[1], s2=(double)(long long)sM[2];
    double m00=(double)(long long)sM[3], m11=(double)(long long)sM[4], m22=(double)(long long)sM[5];
    double m01=(double)(long long)sM[6], m02=(double)(long long)sM[7], m12=(double)(long long)sM[8];
    double w0=W_d1[l*384+c], w1=W_d1[l*384+128+c], w2=W_d1[l*384+256+c];
    double b =b_d1[l*128+c];
    double S = s0*w0+s1*w1+s2*w2;
    double Q = m00*w0*w0+m11*w1*w1+m22*w2*w2 + 2.0*(m01*w0*w1+m02*w0*w2+m12*w1*w2);
    double cnt = (double)NKROWS;
    double mean = S/cnt + b;
    double ex2  = (Q + 2.0*b*S)/cnt + b*b;
    double var  = ex2 - mean*mean;
    float a = g[l*128+c] * (float)(1.0/sqrt(var+1e-5));
    A[l*128+c]=a; C[l*128+c]=beta[l*128+c]-(float)mean*a;
}

// shared helper: reduce NSLOT fp64 partials -> per-channel affine in LDS (threads 0..127 of caller)
__device__ __forceinline__ void affine_reduce(const double* __restrict__ Pin,
        const float* __restrict__ gin, const float* __restrict__ bin, double cntD,
        float* Ash, float* Csh, int c){
    double s=0.0, q=0.0;
#pragma unroll
    for (int k=0;k<NSLOT;k++){ s+=Pin[k*256+c]; q+=Pin[k*256+128+c]; }
    double mean=s/cntD, var=q/cntD-mean*mean;
    float a = gin[c] * (float)(1.0/sqrt(var+1e-5));
    Ash[c]=a; Csh[c]=bin[c]-(float)mean*a;
}

// ---------------------------------------------------------------- GEMM composers
// stage() receives both f32 and packed-f16 affine LDS arrays (valid when AFF prologue ran)
struct CompF32 {
    const float* src;
    __device__ __forceinline__ void stage(u16* As,int R0,int k0,int tid,
            const float*,const float*,const _Float16*,const _Float16*) const {
#pragma unroll
        for (int u=0;u<8;u++){
            int flat=u*256+tid, row=flat>>4, c4=flat&15; int k=k0+c4*4;
            const float4 v=*(const float4*)(src+(size_t)(R0+row)*HD+k);
            ushort4 o; o.x=f2h(v.x); o.y=f2h(v.y); o.z=f2h(v.z); o.w=f2h(v.w);
            *(ushort4*)(As+row*72+c4*4)=o;
        }
    }
};
// pure f16 copy staging (down-gemm input: yb already f16)
struct CompH16Plain {
    const u16* src;
    __device__ __forceinline__ void stage(u16* As,int R0,int k0,int tid,
            const float*,const float*,const _Float16*,const _Float16*) const {
#pragma unroll
        for (int u=0;u<8;u++){
            int flat=u*256+tid, row=flat>>4, c4=flat&15; int k=k0+c4*4;
            *(ushort4*)(As+row*72+c4*4) = *(const ushort4*)(src+(size_t)(R0+row)*HD+k);
        }
    }
};
// packed-f16 BN-affine staging (q/k/v input h16)
struct CompH16Aff {
    const u16* src;
    __device__ __forceinline__ void stage(u16* As,int R0,int k0,int tid,
            const float*,const float*,const _Float16* Ah,const _Float16* Ch) const {
#pragma unroll
        for (int u=0;u<8;u++){
            int flat=u*256+tid, row=flat>>4, c4=flat&15; int k=k0+c4*4;
            const uint2 v=*(const uint2*)(src+(size_t)(R0+row)*HD+k);
            h2v A0=*(const h2v*)(Ah+k), A1=*(const h2v*)(Ah+k+2);
            h2v C0=*(const h2v*)(Ch+k), C1=*(const h2v*)(Ch+k+2);
            uint2 o;
            o.x = bcu(bch2(v.x)*A0 + C0);
            o.y = bcu(bch2(v.y)*A1 + C1);
            *(uint2*)(As+row*72+c4*4)=o;
        }
    }
};
// packed-f16 affine+relu staging (a2)
struct CompH16AffRelu {
    const u16* src;
    __device__ __forceinline__ void stage(u16* As,int R0,int k0,int tid,
            const float*,const float*,const _Float16* Ah,const _Float16* Ch) const {
#pragma unroll
        for (int u=0;u<8;u++){
            int flat=u*256+tid, row=flat>>4, c4=flat&15; int k=k0+c4*4;
            const uint2 v=*(const uint2*)(src+(size_t)(R0+row)*HD+k);
            h2v A0=*(const h2v*)(Ah+k), A1=*(const h2v*)(Ah+k+2);
            h2v C0=*(const h2v*)(Ch+k), C1=*(const h2v*)(Ch+k+2);
            uint2 o;
            o.x = pk_relu(bcu(bch2(v.x)*A0 + C0));
            o.y = pk_relu(bcu(bch2(v.y)*A1 + C1));
            *(uint2*)(As+row*72+c4*4)=o;
        }
    }
};
struct CompPose1 {
    const float* rel; const float* Wd1; const float* bd1; const float* Aa; const float* Ca; // global d1 affine
    __device__ __forceinline__ void stage(u16* As,int R0,int k0,int tid,
            const float*,const float*,const _Float16*,const _Float16*) const {
#pragma unroll
        for (int u=0;u<8;u++){
            int flat=u*256+tid, row=flat>>4, c4=flat&15; int k=k0+c4*4; int R=R0+row;
            float r0=rel[(size_t)R*3], r1=rel[(size_t)R*3+1], r2=rel[(size_t)R*3+2];
            ushort4 o;
#pragma unroll
            for (int j=0;j<4;j++){
                int kk=k+j;
                float x = r0*Wd1[kk] + r1*Wd1[HD+kk] + r2*Wd1[2*HD+kk] + bd1[kk];
                x = fmaxf(x*Aa[kk]+Ca[kk], 0.f);
                ((u16*)&o)[j]=f2h(x);
            }
            *(ushort4*)(As+row*72+c4*4)=o;
        }
    }
};
// packed-f16 (q - kk + BN(pose)) staging (a1)
struct CompA0 {
    const u16* q; const u16* kp; const u16* pose; const int* gidx;
    __device__ __forceinline__ void stage(u16* As,int R0,int k0,int tid,
            const float*,const float*,const _Float16* Ah,const _Float16* Ch) const {
#pragma unroll
        for (int u=0;u<8;u++){
            int flat=u*256+tid, row=flat>>4, c4=flat&15; int k=k0+c4*4; int R=R0+row;
            int n=R>>4; int g=gidx[R];
            const uint2 qv=*(const uint2*)(q +(size_t)n*HD+k);
            const uint2 kv=*(const uint2*)(kp+(size_t)g*HD+k);
            const uint2 pv=*(const uint2*)(pose+(size_t)R*HD+k);
            h2v A0=*(const h2v*)(Ah+k), A1=*(const h2v*)(Ah+k+2);
            h2v C0=*(const h2v*)(Ch+k), C1=*(const h2v*)(Ch+k+2);
            uint2 o;
            o.x = bcu(bch2(qv.x) - bch2(kv.x) + (bch2(pv.x)*A0 + C0));
            o.y = bcu(bch2(qv.y) - bch2(kv.y) + (bch2(pv.y)*A1 + C1));
            *(uint2*)(As+row*72+c4*4)=o;
        }
    }
};

// ---------------------------------------------------------------- GEMM 128x128, K=128, MFMA f16, fused col-stats
// R4 structure: LDS-staged A, 2 K-steps, AFF prologue inline. grid.y selects weight/output.
template<class Comp, bool OUT16, bool HASBIAS, bool STATS, bool AFF>
__global__ __launch_bounds__(256) void gemm128(Comp comp, const u16* __restrict__ Wt,
        const float* __restrict__ bias, void* __restrict__ outp, double* __restrict__ statsP,
        int wtStride, long outStride,
        const double* __restrict__ Pin, const float* __restrict__ gin,
        const float* __restrict__ bin, double cntD){
    __shared__ __align__(16) u16 As[128*72];
    __shared__ __align__(16) u16 Bs[128*72];
    __shared__ float cs2[2][128], cq2[2][128];
    __shared__ float Aaff[128], Caff[128];
    __shared__ _Float16 Ah16[128], Ch16[128];
    const u16* W = Wt + (size_t)blockIdx.y*wtStride;
    u16*   o16 = (u16*)outp   + (size_t)blockIdx.y*outStride;
    float* o32 = (float*)outp + (size_t)blockIdx.y*outStride;
    int tid=threadIdx.x;
    if (AFF){
        if (tid<128){
            affine_reduce(Pin, gin, bin, cntD, Aaff, Caff, tid);
            Ah16[tid]=(_Float16)Aaff[tid]; Ch16[tid]=(_Float16)Caff[tid];
        }
        __syncthreads();
    }
    int R0=blockIdx.x*128;
    int lane=tid&63, wave=tid>>6, quad=lane>>4, r16=lane&15;
    int wm=wave>>1, wn=wave&1;
    floatx4 acc[4][4]={};
#pragma unroll
    for (int ks=0;ks<2;ks++){
        int k0=ks*64;
        comp.stage(As,R0,k0,tid,Aaff,Caff,Ah16,Ch16);
#pragma unroll
        for (int u=0;u<4;u++){
            int flat=u*256+tid, n=flat>>3, c8=flat&7;
            *(int4*)(Bs+n*72+c8*8) = *(const int4*)(W+n*HD+k0+c8*8);
        }
        __syncthreads();
#pragma unroll
        for (int kk2=0;kk2<2;kk2++){
            half8 aF[4], bF[4];
#pragma unroll
            for (int mi=0;mi<4;mi++) aF[mi]=*(const half8*)(As+(wm*64+mi*16+r16)*72 + kk2*32+quad*8);
#pragma unroll
            for (int ni=0;ni<4;ni++) bF[ni]=*(const half8*)(Bs+(wn*64+ni*16+r16)*72 + kk2*32+quad*8);
#pragma unroll
            for (int mi=0;mi<4;mi++)
#pragma unroll
                for (int ni=0;ni<4;ni++)
                    acc[mi][ni]=__builtin_amdgcn_mfma_f32_16x16x32_f16(aF[mi],bF[ni],acc[mi][ni],0,0,0);
        }
        __syncthreads();
    }
    float sAcc[4]={0,0,0,0}, qAcc[4]={0,0,0,0};
#pragma unroll
    for (int mi=0;mi<4;mi++)
#pragma unroll
        for (int ni=0;ni<4;ni++){
            int col=wn*64+ni*16+r16;
            float bv = HASBIAS ? bias[col] : 0.f;
#pragma unroll
            for (int rg=0;rg<4;rg++){
                int row=R0+wm*64+mi*16+quad*4+rg;
                float v=acc[mi][ni][rg]+bv;
                if (STATS){ sAcc[ni]+=v; qAcc[ni]+=v*v; }
                if (OUT16) o16[(size_t)row*HD+col]=f2h(v);
                else       o32[(size_t)row*HD+col]=v;
            }
        }
    if (STATS){
#pragma unroll
        for (int ni=0;ni<4;ni++){
            float s=sAcc[ni], q=qAcc[ni];
            s += __shfl_xor(s,16,64); s += __shfl_xor(s,32,64);
            q += __shfl_xor(q,16,64); q += __shfl_xor(q,32,64);
            if (quad==0){
                int col=wn*64+ni*16+r16;
                cs2[wm][col]=s; cq2[wm][col]=q;
            }
        }
        __syncthreads();
        if (tid<128){
            int slot = blockIdx.x & (NSLOT-1);
            unsafeAtomicAdd(&statsP[slot*256+tid],     (double)(cs2[0][tid]+cs2[1][tid]));
            unsafeAtomicAdd(&statsP[slot*256+128+tid], (double)(cq2[0][tid]+cq2[1][tid]));
        }
    }
}

// ---------------------------------------------------------------- softmax-aggregate + residual
// 256 threads: 4 points x 64 channel-pairs; grid NPTS/4. Prologue computes BOTH affines
// (g2 by threads 0-127, d2 by threads 128-255). Output f16 (bit-identical into down-gemm,
// which converted to f16 during staging anyway).
__global__ __launch_bounds__(256) void aggregate(const u16* __restrict__ a2, const u16* __restrict__ pose,
        const u16* __restrict__ vv, const int* __restrict__ gidx,
        const double* __restrict__ Pg2, const float* __restrict__ g_g2, const float* __restrict__ b_g2,
        const double* __restrict__ Pd2, const float* __restrict__ g_d2, const float* __restrict__ b_d2,
        u16* __restrict__ y){
    __shared__ float Ag2s[128], Cg2s[128], Ad2s[128], Cd2s[128];
    int t=threadIdx.x;
    {
        int cc=t&127;
        const double* Pp = (t<128)? Pg2 : Pd2;
        const float*  gg = (t<128)? g_g2 : g_d2;
        const float*  bb = (t<128)? b_g2 : b_d2;
        float* Adst = (t<128)? Ag2s : Ad2s;
        float* Cdst = (t<128)? Cg2s : Cd2s;
        affine_reduce(Pp, gg, bb, (double)NKROWS, Adst, Cdst, cc);
    }
    __syncthreads();
    int c=(t&63)*2, h=t>>6;
    int n=blockIdx.x*4+h;
    float sA0=Ag2s[c], sC0=Cg2s[c], pA0=Ad2s[c], pC0=Cd2s[c];
    float sA1=Ag2s[c+1], sC1=Cg2s[c+1], pA1=Ad2s[c+1], pC1=Cd2s[c+1];
    float av0[16], av1[16]; float m0=-1e30f, m1=-1e30f;
#pragma unroll
    for (int k=0;k<16;k++){
        ushort2 tt=*(const ushort2*)(a2+((size_t)n*16+k)*HD+c);
        float a0=h2f(tt.x)*sA0+sC0, a1=h2f(tt.y)*sA1+sC1;
        av0[k]=a0; av1[k]=a1; m0=fmaxf(m0,a0); m1=fmaxf(m1,a1);
    }
    float sum0=0.f, sum1=0.f;
#pragma unroll
    for (int k=0;k<16;k++){
        float e0=__expf(av0[k]-m0), e1=__expf(av1[k]-m1);
        av0[k]=e0; av1[k]=e1; sum0+=e0; sum1+=e1;
    }
    float acc0=0.f, acc1=0.f;
#pragma unroll
    for (int k=0;k<16;k++){
        int g=gidx[n*16+k];
        ushort2 pt=*(const ushort2*)(pose+((size_t)n*16+k)*HD+c);
        ushort2 vt=*(const ushort2*)(vv+(size_t)g*HD+c);
        acc0 += av0[k]*(h2f(pt.x)*pA0+pC0 + h2f(vt.x));
        acc1 += av1[k]*(h2f(pt.y)*pA1+pC1 + h2f(vt.y));
    }
    ushort2 o; o.x=f2h(acc0/sum0); o.y=f2h(acc1/sum1);
    *(ushort2*)(y+(size_t)n*HD+c)=o;
}

// float4-vectorized residual with inline dn-affine; grid NPTS*HD/1024
__global__ __launch_bounds__(256) void residual(const float* __restrict__ ydown,
        const double* __restrict__ Pin, const float* __restrict__ gin, const float* __restrict__ bin,
        const float* __restrict__ fin, float* __restrict__ fout){
    __shared__ float Ash[128], Csh[128];
    int tid=threadIdx.x;
    if (tid<128) affine_reduce(Pin, gin, bin, (double)NPTS, Ash, Csh, tid);
    __syncthreads();
    size_t i=((size_t)blockIdx.x*256+tid)*4; int c=(int)(i&127);
    float4 yv=*(const float4*)(ydown+i);
    float4 fv=*(const float4*)(fin+i);
    float4 o;
    o.x=yv.x*Ash[c]  +Csh[c]  +fv.x;
    o.y=yv.y*Ash[c+1]+Csh[c+1]+fv.y;
    o.z=yv.z*Ash[c+2]+Csh[c+2]+fv.z;
    o.w=yv.w*Ash[c+3]+Csh[c+3]+fv.w;
    *(float4*)(fout+i)=o;
}

// ---------------------------------------------------------------- launch
extern "C" void kernel_launch(void* const* d_in, const int* in_sizes, int n_in,
                              void* d_out, int out_size, void* d_ws, size_t ws_size,
                              hipStream_t stream){
    const int*   coords=(const int*)d_in[0];
    const float* feats=(const float*)d_in[1];
    const float* W_top=(const float*)d_in[2];
    const float* g_top=(const float*)d_in[3];
    const float* bt_top=(const float*)d_in[4];
    const float* W_phi=(const float*)d_in[5];
    const float* W_psi=(const float*)d_in[6];
    const float* W_alp=(const float*)d_in[7];
    const float* W_d1=(const float*)d_in[8];
    const float* b_d1=(const float*)d_in[9];
    const float* g_d1=(const float*)d_in[10];
    const float* bt_d1=(const float*)d_in[11];
    const float* W_d2=(const float*)d_in[12];
    const float* b_d2=(const float*)d_in[13];
    const float* g_d2=(const float*)d_in[14];
    const float* bt_d2=(const float*)d_in[15];
    const float* W_g1=(const float*)d_in[16];
    const float* b_g1=(const float*)d_in[17];
    const float* g_g1=(const float*)d_in[18];
    const float* bt_g1=(const float*)d_in[19];
    const float* W_g2=(const float*)d_in[20];
    const float* b_g2=(const float*)d_in[21];
    const float* g_g2=(const float*)d_in[22];
    const float* bt_g2=(const float*)d_in[23];
    const float* W_dn=(const float*)d_in[24];
    const float* g_dn=(const float*)d_in[25];
    const float* bt_dn=(const float*)d_in[26];

    char* ws=(char*)d_ws;
    size_t off=0;
    auto carve=[&](size_t bytes)->char*{ char* p=ws+off; off=(off+bytes+255)&~(size_t)255; return p; };
    u32*    pc    =(u32*)   carve((size_t)NPTS*4);
    int*    idxg  =(int*)   carve((size_t)NKROWS*4);
    float*  rel   =(float*) carve((size_t)NKROWS*3*4);
    u16*    h16   =(u16*)   carve((size_t)NPTS*HD*2);
    u16*    qb    =(u16*)   carve((size_t)3*NPTS*HD*2);   // q | kpsi | v contiguous
    u16*    kpb   = qb + (size_t)NPTS*HD;
    u16*    vvb   = qb + (size_t)2*NPTS*HD;
    u16*    yb    =(u16*)   carve((size_t)NPTS*HD*2);     // f16 aggregate output
    float*  ydown =(float*) carve((size_t)NPTS*HD*4);
    float*  fbuf  =(float*) carve((size_t)NPTS*HD*4);
    u16*    wt    =(u16*)   carve((size_t)8*2*16384*2);
    char*   stats =         carve((size_t)NREG*NSLOT*256*8 + 256);  // P regions + sM
    double* P     =(double*)stats;
    u64*    sM    =(u64*)(stats + (size_t)NREG*NSLOT*256*8);
    float*  aff   =(float*) carve(4096);                  // d1 affine only
    float *A_d1=aff, *C_d1=aff+256;
    u16*    pose2 =(u16*)   carve((size_t)NKROWS*HD*2);
    u16*    abuf  =(u16*)   carve((size_t)NKROWS*HD*2);
    if (ws_size < off) return;

    // stats region: stage in {0:top,1:d2,2:g1,3:g2,4:dn} x layer
    auto Preg=[&](int stage,int l)->double*{ return P + (size_t)(stage*2+l)*(NSLOT*256); };

    hipMemsetAsync(stats, 0, (size_t)NREG*NSLOT*256*8 + 256, stream);
    pack_coords<<<dim3(NPTS/256),dim3(256),0,stream>>>(coords, pc);
    WPtrs wp{{W_top,W_phi,W_psi,W_alp,W_d2,W_g1,W_g2,W_dn}};
    prep_weights<<<dim3(8*2*16384/256),dim3(256),0,stream>>>(wp, wt);
    knn3<<<dim3(2048),dim3(512),0,stream>>>(pc, idxg, rel, sM);
    finalize_d1<<<dim3(1),dim3(256),0,stream>>>(sM, W_d1, b_d1, g_d1, bt_d1, A_d1, C_d1);

    const float* fin=feats;
    for (int l=0;l<2;l++){
        const u16* wt_top=wt+(0*2+l)*16384; const u16* wt_phi=wt+(1*2+l)*16384;
        const u16* wt_d2 =wt+(4*2+l)*16384; const u16* wt_g1 =wt+(5*2+l)*16384;
        const u16* wt_g2 =wt+(6*2+l)*16384; const u16* wt_dn =wt+(7*2+l)*16384;

        // h16 = f @ W_top (f16 out, stats -> P(top,l))
        gemm128<CompF32,true,false,true,false><<<dim3(NPTS/128),dim3(256),0,stream>>>(
            CompF32{fin}, wt_top, nullptr, h16, Preg(0,l), 0, 0, nullptr, nullptr, nullptr, 0.0);

        // q / kpsi / vv in ONE launch; top-affine computed inline from P(top,l) (packed staging)
        gemm128<CompH16Aff,true,false,false,true><<<dim3(NPTS/128,3),dim3(256),0,stream>>>(
            CompH16Aff{h16}, wt_phi, nullptr, qb, nullptr, 2*16384, (long)NPTS*HD,
            Preg(0,l), g_top+l*128, bt_top+l*128, (double)NPTS);

        // pose2 = relu(BN1(rel@W_d1+b_d1)) @ W_d2 + b_d2 (stats -> P(d2,l))
        gemm128<CompPose1,true,true,true,false><<<dim3(NKROWS/128),dim3(256),0,stream>>>(
            CompPose1{rel, W_d1+l*384, b_d1+l*128, A_d1+l*128, C_d1+l*128}, wt_d2, b_d2+l*128, pose2,
            Preg(1,l), 0, 0, nullptr, nullptr, nullptr, 0.0);

        // a1 = (q - kpsi[g] + BN(pose2)) @ W_g1 + b_g1; d2-affine inline (packed); stats -> P(g1,l)
        gemm128<CompA0,true,true,true,true><<<dim3(NKROWS/128),dim3(256),0,stream>>>(
            CompA0{qb,kpb,pose2,idxg}, wt_g1, b_g1+l*128, abuf, Preg(2,l), 0, 0,
            Preg(1,l), g_d2+l*128, bt_d2+l*128, (double)NKROWS);

        // a2 = relu(BN(a1)) @ W_g2 + b_g2 (in-place); g1-affine inline (packed); stats -> P(g2,l)
        gemm128<CompH16AffRelu,true,true,true,true><<<dim3(NKROWS/128),dim3(256),0,stream>>>(
            CompH16AffRelu{abuf}, wt_g2, b_g2+l*128, abuf, Preg(3,l), 0, 0,
            Preg(2,l), g_g1+l*128, bt_g1+l*128, (double)NKROWS);

        // softmax over K + aggregate; g2- and d2-affines inline; f16 output
        aggregate<<<dim3(NPTS/4),dim3(256),0,stream>>>(abuf, pose2, vvb, idxg,
            Preg(3,l), g_g2+l*128, bt_g2+l*128, Preg(1,l), g_d2+l*128, bt_d2+l*128, yb);

        // y @ W_down (f16 in, pure-copy staging; stats -> P(dn,l)) ; BN+residual with inline dn-affine
        gemm128<CompH16Plain,false,false,true,false><<<dim3(NPTS/128),dim3(256),0,stream>>>(
            CompH16Plain{yb}, wt_dn, nullptr, ydown, Preg(4,l), 0, 0, nullptr, nullptr, nullptr, 0.0);
        residual<<<dim3(NPTS*HD/1024),dim3(256),0,stream>>>(ydown,
            Preg(4,l), g_dn+l*128, bt_dn+l*128, fin, (l==1)?(float*)d_out:fbuf);
        fin=fbuf;
    }
}

// Round 9
// 511.341 us; speedup vs baseline: 1.0131x; 1.0131x over previous
//
#include <hip/hip_runtime.h>

using u16 = unsigned short;
using u32 = unsigned int;
using u64 = unsigned long long;

#define NPTS   16384
#define NPER   8192
#define KNN    16
#define NKROWS (NPTS*KNN)
#define HD     128
#define CAP    208   // per-wave candidate buffer slots
#define NSLOT  16    // fp64 stats partial slots
#define NREG   10    // stats regions: 5 stages x 2 layers

typedef _Float16 half8 __attribute__((ext_vector_type(8)));
typedef float    floatx4 __attribute__((ext_vector_type(4)));
typedef short          s16x2 __attribute__((ext_vector_type(2)));
typedef unsigned short u16x2 __attribute__((ext_vector_type(2)));
typedef _Float16       h2v   __attribute__((ext_vector_type(2)));

__device__ __forceinline__ u16  f2h(float f){ _Float16 h=(_Float16)f; return __builtin_bit_cast(u16,h); }
__device__ __forceinline__ float h2f(u16 u){ return (float)__builtin_bit_cast(_Float16,u); }
__device__ __forceinline__ u32 umin32(u32 a,u32 b){ return a<b?a:b; }
__device__ __forceinline__ u32 mbcnt64(u64 m){
    return __builtin_amdgcn_mbcnt_hi((u32)(m>>32), __builtin_amdgcn_mbcnt_lo((u32)m,0));
}
__device__ __forceinline__ h2v bch2(u32 x){ return __builtin_bit_cast(h2v,x); }
__device__ __forceinline__ u32 bcu(h2v x){ return __builtin_bit_cast(u32,x); }
// packed f16 relu: v_pk_max_f16 with a zero VGPR
__device__ __forceinline__ u32 pk_relu(u32 x){
    u32 r;
    asm("v_pk_max_f16 %0, %1, %2" : "=v"(r) : "v"(x), "v"(0u));
    return r;
}
// dx*dx + dy*dy + c via v_dot2_i32_i16 when available
__device__ __forceinline__ int sdot2_acc(s16x2 a, int c){
#if __has_builtin(__builtin_amdgcn_sdot2)
    return __builtin_amdgcn_sdot2(a, a, c, false);
#else
    return (int)a.x*(int)a.x + (int)a.y*(int)a.y + c;
#endif
}

// ---------------------------------------------------------------- prep
__global__ __launch_bounds__(256) void pack_coords(const int* __restrict__ coords, u32* __restrict__ pc){
    int i = blockIdx.x*256 + threadIdx.x;
    pc[i] = (u32)coords[3*i] | ((u32)coords[3*i+1]<<8) | ((u32)coords[3*i+2]<<16);
}

struct WPtrs { const float* p[8]; };
// wt[(t*2+l)*16384 + n*128 + k] = f16( W_t[l][k][n] )
__global__ __launch_bounds__(256) void prep_weights(WPtrs wp, u16* __restrict__ wt){
    int idx = blockIdx.x*256 + threadIdx.x;
    int t = idx>>15, rem = idx&32767;
    int l = rem>>14, e = rem&16383;
    int n = e>>7, k = e&127;
    wt[idx] = f2h(wp.p[t][l*16384 + k*128 + n]);
}

// ---------------------------------------------------------------- KNN v6: packed-i16 math + ballot-select tighten (proven R4)
__global__ __launch_bounds__(512) void knn3(const u32* __restrict__ pc, int* __restrict__ idx_g,
                                            float* __restrict__ rel, u64* __restrict__ sM){
    __shared__ u32 sc[NPER];
    __shared__ u32 buf[8][CAP];
    __shared__ u64 red[9];
    int tid = threadIdx.x;
    int wave = tid>>6, lane = tid&63;
    int scene = blockIdx.x >> 10;                 // 1024 blocks per scene
    int q = (blockIdx.x & 1023)*8 + wave;

    const uint4* s4 = (const uint4*)(pc + scene*NPER);
#pragma unroll
    for (int i=0;i<4;i++) ((uint4*)sc)[tid + i*512] = s4[tid + i*512];
    if (tid<9) red[tid]=0;
    if (lane<16) buf[wave][lane]=0xFFFFFFFFu;
    __syncthreads();

    u32 qp = sc[q];
    int qx=(int)(qp&255), qy=(int)((qp>>8)&255), qz=(int)((qp>>16)&255);
    s16x2 qxy = __builtin_bit_cast(s16x2, __builtin_amdgcn_perm(0u, qp, 0x04010400u));
    s16x2 qzz = __builtin_bit_cast(s16x2, (qp>>16) * 0x00010001u);
    u32 thresh = 0xFFFFFFFFu;
    u32 td2 = thresh >> 13;
    u32 cnt = 16;                                  // buf[0..15] = current top-16 set

    auto tighten = [&](){
        u32 v0 = (lane      < (int)cnt) ? buf[wave][lane]      : 0xFFFFFFFFu;
        u32 v1 = (lane+64   < (int)cnt) ? buf[wave][lane+64]   : 0xFFFFFFFFu;
        u32 v2 = (lane+128  < (int)cnt) ? buf[wave][lane+128]  : 0xFFFFFFFFu;
        u32 v3 = (lane+192  < (int)cnt) ? buf[wave][lane+192]  : 0xFFFFFFFFu;
        u32 T = 0;
#pragma unroll
        for (int b=29;b>=0;b--){
            u32 Tt = T | (1u<<b);
            int c = __popcll(__ballot(v0<Tt)) + __popcll(__ballot(v1<Tt))
                  + __popcll(__ballot(v2<Tt)) + __popcll(__ballot(v3<Tt));
            if (c < 16) T = Tt;                    // wave-uniform (scalar) update
        }
        u64 m0=__ballot(v0<=T), m1=__ballot(v1<=T), m2=__ballot(v2<=T), m3=__ballot(v3<=T);
        u32 b0=(u32)__popcll(m0), b1=(u32)__popcll(m1), b2=(u32)__popcll(m2);
        if (v0<=T) buf[wave][mbcnt64(m0)]=v0;
        if (v1<=T) buf[wave][b0+mbcnt64(m1)]=v1;
        if (v2<=T) buf[wave][b0+b1+mbcnt64(m2)]=v2;
        if (v3<=T) buf[wave][b0+b1+b2+mbcnt64(m3)]=v3;
        cnt = 16;
        thresh = T;
        td2 = T >> 13;
    };

    int lane2 = lane*2;
    uint2 p2 = ((const uint2*)sc)[lane];
    for (int t=0;t<64;t++){
        uint2 cur = p2;
        if (t<63) p2 = ((const uint2*)sc)[(t+1)*64+lane];
        u32 pa = cur.x, pb = cur.y;
        s16x2 xy0 = __builtin_bit_cast(s16x2, __builtin_amdgcn_perm(0u, pa, 0x04010400u));
        s16x2 xy1 = __builtin_bit_cast(s16x2, __builtin_amdgcn_perm(0u, pb, 0x04010400u));
        u32 zzr = __builtin_amdgcn_perm(pb, pa, 0x00060002u) & 0x00FF00FFu;
        s16x2 dzz = __builtin_bit_cast(s16x2, zzr) - qzz;        // both dz in one pk_sub
        u16x2 dzu = __builtin_bit_cast(u16x2, dzz);
        u16x2 zsq = dzu*dzu;                                     // dz^2 <= 39601 exact mod 2^16
        u32 zb = __builtin_bit_cast(u32, zsq);
        s16x2 dxy0 = xy0 - qxy;
        s16x2 dxy1 = xy1 - qxy;
        u32 d2_0 = (u32)sdot2_acc(dxy0, (int)(zb & 0xFFFFu));
        u32 d2_1 = (u32)sdot2_acc(dxy1, (int)(zb >> 16));
        u64 m0 = __ballot(d2_0 <= td2);
        if (m0){
            int base = t*128 + lane2;
            if (d2_0 <= td2) buf[wave][cnt + mbcnt64(m0)] = (d2_0<<13) + (u32)base;
            cnt += (u32)__popcll(m0);
            if (cnt > CAP-64) tighten();
        }
        u64 m1 = __ballot(d2_1 <= td2);
        if (m1){
            int base = t*128 + lane2;
            if (d2_1 <= td2) buf[wave][cnt + mbcnt64(m1)] = (d2_1<<13) + (u32)(base+1);
            cnt += (u32)__popcll(m1);
            if (cnt > CAP-64) tighten();
        }
    }
    tighten();                                     // exact top-16 (unsorted) in buf[0..15]

    // sort the 16 keys ascending: rank = #(keys smaller), keys unique
    {
        u32 myk = buf[wave][lane & 15];
        u32 rank = 0;
#pragma unroll
        for (int j=0;j<16;j++){ u32 o = buf[wave][j]; rank += (o < myk) ? 1u : 0u; }
        if (lane < 16) buf[wave][rank] = myk;
    }

    // epilogue: emit idx/rel + moment sums (for analytic d1-BN)
    int n = scene*NPER + q;
    u32 key = buf[wave][lane & 15];
    int dx=0,dy=0,dz=0;
    if (lane<16){
        int j = (int)(key & 8191u);
        idx_g[(size_t)n*KNN + lane] = scene*NPER + j;
        u32 p = sc[j];
        dx=(int)(p&255)-qx; dy=(int)((p>>8)&255)-qy; dz=(int)((p>>16)&255)-qz;
        size_t ro = ((size_t)n*KNN+lane)*3;
        rel[ro]=(float)dx; rel[ro+1]=(float)dy; rel[ro+2]=(float)dz;
    }
    int arr[9] = {dx,dy,dz, dx*dx,dy*dy,dz*dz, dx*dy,dx*dz,dy*dz};
#pragma unroll
    for (int o=32;o>=1;o>>=1)
#pragma unroll
        for (int j=0;j<9;j++) arr[j] += __shfl_xor(arr[j], o, 64);
    if (lane==0)
#pragma unroll
        for (int j=0;j<9;j++) atomicAdd(&red[j], (u64)(long long)arr[j]);
    __syncthreads();
    if (tid<9) atomicAdd(&sM[tid], red[tid]);
}

// analytic BN affine for the 3->H layer (runs once)
__global__ __launch_bounds__(256) void finalize_d1(const u64* __restrict__ sM, const float* __restrict__ W_d1,
        const float* __restrict__ b_d1, const float* __restrict__ g, const float* __restrict__ beta,
        float* __restrict__ A, float* __restrict__ C){
    int tid=threadIdx.x; int l=tid>>7, c=tid&127;
    double s0=(double)(long long)sM[0], s1=(double)(long long)sM[1], s2=(double)(long long)sM[2];
    double m00=(double)(long long)sM[3], m11=(double)(long long)sM[4], m22=(double)(long long)sM[5];
    double m01=(double)(long long)sM[6], m02=(double)(long long)sM[7], m12=(double)(long long)sM[8];
    double w0=W_d1[l*384+c], w1=W_d1[l*384+128+c], w2=W_d1[l*384+256+c];
    double b =b_d1[l*128+c];
    double S = s0*w0+s1*w1+s2*w2;
    double Q = m00*w0*w0+m11*w1*w1+m22*w2*w2 + 2.0*(m01*w0*w1+m02*w0*w2+m12*w1*w2);
    double cnt = (double)NKROWS;
    double mean = S/cnt + b;
    double ex2  = (Q + 2.0*b*S)/cnt + b*b;
    double var  = ex2 - mean*mean;
    float a = g[l*128+c] * (float)(1.0/sqrt(var+1e-5));
    A[l*128+c]=a; C[l*128+c]=beta[l*128+c]-(float)mean*a;
}

// shared helper: reduce NSLOT fp64 partials -> per-channel affine in LDS (threads 0..127 of caller)
__device__ __forceinline__ void affine_reduce(const double* __restrict__ Pin,
        const float* __restrict__ gin, const float* __restrict__ bin, double cntD,
        float* Ash, float* Csh, int c){
    double s=0.0, q=0.0;
#pragma unroll
    for (int k=0;k<NSLOT;k++){ s+=Pin[k*256+c]; q+=Pin[k*256+128+c]; }
    double mean=s/cntD, var=q/cntD-mean*mean;
    float a = gin[c] * (float)(1.0/sqrt(var+1e-5));
    Ash[c]=a; Csh[c]=bin[c]-(float)mean*a;
}

// ---------------------------------------------------------------- GEMM composers
// stage() receives both f32 and packed-f16 affine LDS arrays (valid when AFF prologue ran)
struct CompF32 {
    const float* src;
    __device__ __forceinline__ void stage(u16* As,int R0,int k0,int tid,
            const float*,const float*,const _Float16*,const _Float16*) const {
#pragma unroll
        for (int u=0;u<8;u++){
            int flat=u*256+tid, row=flat>>4, c4=flat&15; int k=k0+c4*4;
            const float4 v=*(const float4*)(src+(size_t)(R0+row)*HD+k);
            ushort4 o; o.x=f2h(v.x); o.y=f2h(v.y); o.z=f2h(v.z); o.w=f2h(v.w);
            *(ushort4*)(As+row*72+c4*4)=o;
        }
    }
};
// pure f16 copy staging (down-gemm input: yb already f16)
struct CompH16Plain {
    const u16* src;
    __device__ __forceinline__ void stage(u16* As,int R0,int k0,int tid,
            const float*,const float*,const _Float16*,const _Float16*) const {
#pragma unroll
        for (int u=0;u<8;u++){
            int flat=u*256+tid, row=flat>>4, c4=flat&15; int k=k0+c4*4;
            *(ushort4*)(As+row*72+c4*4) = *(const ushort4*)(src+(size_t)(R0+row)*HD+k);
        }
    }
};
// packed-f16 BN-affine staging (q/k/v input h16)
struct CompH16Aff {
    const u16* src;
    __device__ __forceinline__ void stage(u16* As,int R0,int k0,int tid,
            const float*,const float*,const _Float16* Ah,const _Float16* Ch) const {
#pragma unroll
        for (int u=0;u<8;u++){
            int flat=u*256+tid, row=flat>>4, c4=flat&15; int k=k0+c4*4;
            const uint2 v=*(const uint2*)(src+(size_t)(R0+row)*HD+k);
            h2v A0=*(const h2v*)(Ah+k), A1=*(const h2v*)(Ah+k+2);
            h2v C0=*(const h2v*)(Ch+k), C1=*(const h2v*)(Ch+k+2);
            uint2 o;
            o.x = bcu(bch2(v.x)*A0 + C0);
            o.y = bcu(bch2(v.y)*A1 + C1);
            *(uint2*)(As+row*72+c4*4)=o;
        }
    }
};
// packed-f16 affine+relu staging (a2)
struct CompH16AffRelu {
    const u16* src;
    __device__ __forceinline__ void stage(u16* As,int R0,int k0,int tid,
            const float*,const float*,const _Float16* Ah,const _Float16* Ch) const {
#pragma unroll
        for (int u=0;u<8;u++){
            int flat=u*256+tid, row=flat>>4, c4=flat&15; int k=k0+c4*4;
            const uint2 v=*(const uint2*)(src+(size_t)(R0+row)*HD+k);
            h2v A0=*(const h2v*)(Ah+k), A1=*(const h2v*)(Ah+k+2);
            h2v C0=*(const h2v*)(Ch+k), C1=*(const h2v*)(Ch+k+2);
            uint2 o;
            o.x = pk_relu(bcu(bch2(v.x)*A0 + C0));
            o.y = pk_relu(bcu(bch2(v.y)*A1 + C1));
            *(uint2*)(As+row*72+c4*4)=o;
        }
    }
};
struct CompPose1 {
    const float* rel; const float* Wd1; const float* bd1; const float* Aa; const float* Ca; // global d1 affine
    __device__ __forceinline__ void stage(u16* As,int R0,int k0,int tid,
            const float*,const float*,const _Float16*,const _Float16*) const {
#pragma unroll
        for (int u=0;u<8;u++){
            int flat=u*256+tid, row=flat>>4, c4=flat&15; int k=k0+c4*4; int R=R0+row;
            float r0=rel[(size_t)R*3], r1=rel[(size_t)R*3+1], r2=rel[(size_t)R*3+2];
            ushort4 o;
#pragma unroll
            for (int j=0;j<4;j++){
                int kk=k+j;
                float x = r0*Wd1[kk] + r1*Wd1[HD+kk] + r2*Wd1[2*HD+kk] + bd1[kk];
                x = fmaxf(x*Aa[kk]+Ca[kk], 0.f);
                ((u16*)&o)[j]=f2h(x);
            }
            *(ushort4*)(As+row*72+c4*4)=o;
        }
    }
};
// packed-f16 (q - kk + BN(pose)) staging (a1)
struct CompA0 {
    const u16* q; const u16* kp; const u16* pose; const int* gidx;
    __device__ __forceinline__ void stage(u16* As,int R0,int k0,int tid,
            const float*,const float*,const _Float16* Ah,const _Float16* Ch) const {
#pragma unroll
        for (int u=0;u<8;u++){
            int flat=u*256+tid, row=flat>>4, c4=flat&15; int k=k0+c4*4; int R=R0+row;
            int n=R>>4; int g=gidx[R];
            const uint2 qv=*(const uint2*)(q +(size_t)n*HD+k);
            const uint2 kv=*(const uint2*)(kp+(size_t)g*HD+k);
            const uint2 pv=*(const uint2*)(pose+(size_t)R*HD+k);
            h2v A0=*(const h2v*)(Ah+k), A1=*(const h2v*)(Ah+k+2);
            h2v C0=*(const h2v*)(Ch+k), C1=*(const h2v*)(Ch+k+2);
            uint2 o;
            o.x = bcu(bch2(qv.x) - bch2(kv.x) + (bch2(pv.x)*A0 + C0));
            o.y = bcu(bch2(qv.y) - bch2(kv.y) + (bch2(pv.y)*A1 + C1));
            *(uint2*)(As+row*72+c4*4)=o;
        }
    }
};

// ---------------------------------------------------------------- GEMM 128x128, K=128, MFMA f16, fused col-stats
// R4 structure: LDS-staged A, 2 K-steps, AFF prologue inline. grid.y selects weight/output.
template<class Comp, bool OUT16, bool HASBIAS, bool STATS, bool AFF>
__global__ __launch_bounds__(256) void gemm128(Comp comp, const u16* __restrict__ Wt,
        const float* __restrict__ bias, void* __restrict__ outp, double* __restrict__ statsP,
        int wtStride, long outStride,
        const double* __restrict__ Pin, const float* __restrict__ gin,
        const float* __restrict__ bin, double cntD){
    __shared__ __align__(16) u16 As[128*72];
    __shared__ __align__(16) u16 Bs[128*72];
    __shared__ float cs2[2][128], cq2[2][128];
    __shared__ float Aaff[128], Caff[128];
    __shared__ _Float16 Ah16[128], Ch16[128];
    const u16* W = Wt + (size_t)blockIdx.y*wtStride;
    u16*   o16 = (u16*)outp   + (size_t)blockIdx.y*outStride;
    float* o32 = (float*)outp + (size_t)blockIdx.y*outStride;
    int tid=threadIdx.x;
    if (AFF){
        if (tid<128){
            affine_reduce(Pin, gin, bin, cntD, Aaff, Caff, tid);
            Ah16[tid]=(_Float16)Aaff[tid]; Ch16[tid]=(_Float16)Caff[tid];
        }
        __syncthreads();
    }
    int R0=blockIdx.x*128;
    int lane=tid&63, wave=tid>>6, quad=lane>>4, r16=lane&15;
    int wm=wave>>1, wn=wave&1;
    floatx4 acc[4][4]={};
#pragma unroll
    for (int ks=0;ks<2;ks++){
        int k0=ks*64;
        comp.stage(As,R0,k0,tid,Aaff,Caff,Ah16,Ch16);
#pragma unroll
        for (int u=0;u<4;u++){
            int flat=u*256+tid, n=flat>>3, c8=flat&7;
            *(int4*)(Bs+n*72+c8*8) = *(const int4*)(W+n*HD+k0+c8*8);
        }
        __syncthreads();
#pragma unroll
        for (int kk2=0;kk2<2;kk2++){
            half8 aF[4], bF[4];
#pragma unroll
            for (int mi=0;mi<4;mi++) aF[mi]=*(const half8*)(As+(wm*64+mi*16+r16)*72 + kk2*32+quad*8);
#pragma unroll
            for (int ni=0;ni<4;ni++) bF[ni]=*(const half8*)(Bs+(wn*64+ni*16+r16)*72 + kk2*32+quad*8);
#pragma unroll
            for (int mi=0;mi<4;mi++)
#pragma unroll
                for (int ni=0;ni<4;ni++)
                    acc[mi][ni]=__builtin_amdgcn_mfma_f32_16x16x32_f16(aF[mi],bF[ni],acc[mi][ni],0,0,0);
        }
        __syncthreads();
    }
    float sAcc[4]={0,0,0,0}, qAcc[4]={0,0,0,0};
#pragma unroll
    for (int mi=0;mi<4;mi++)
#pragma unroll
        for (int ni=0;ni<4;ni++){
            int col=wn*64+ni*16+r16;
            float bv = HASBIAS ? bias[col] : 0.f;
#pragma unroll
            for (int rg=0;rg<4;rg++){
                int row=R0+wm*64+mi*16+quad*4+rg;
                float v=acc[mi][ni][rg]+bv;
                if (STATS){ sAcc[ni]+=v; qAcc[ni]+=v*v; }
                if (OUT16) o16[(size_t)row*HD+col]=f2h(v);
                else       o32[(size_t)row*HD+col]=v;
            }
        }
    if (STATS){
#pragma unroll
        for (int ni=0;ni<4;ni++){
            float s=sAcc[ni], q=qAcc[ni];
            s += __shfl_xor(s,16,64); s += __shfl_xor(s,32,64);
            q += __shfl_xor(q,16,64); q += __shfl_xor(q,32,64);
            if (quad==0){
                int col=wn*64+ni*16+r16;
                cs2[wm][col]=s; cq2[wm][col]=q;
            }
        }
        __syncthreads();
        if (tid<128){
            int slot = blockIdx.x & (NSLOT-1);
            unsafeAtomicAdd(&statsP[slot*256+tid],     (double)(cs2[0][tid]+cs2[1][tid]));
            unsafeAtomicAdd(&statsP[slot*256+128+tid], (double)(cq2[0][tid]+cq2[1][tid]));
        }
    }
}

// ---------------------------------------------------------------- softmax-aggregate + residual
// 256 threads: 4 points x 64 channel-pairs; grid NPTS/4. Prologue computes BOTH affines
// (g2 by threads 0-127, d2 by threads 128-255). Output f16 (bit-identical into down-gemm,
// which converted to f16 during staging anyway).
__global__ __launch_bounds__(256) void aggregate(const u16* __restrict__ a2, const u16* __restrict__ pose,
        const u16* __restrict__ vv, const int* __restrict__ gidx,
        const double* __restrict__ Pg2, const float* __restrict__ g_g2, const float* __restrict__ b_g2,
        const double* __restrict__ Pd2, const float* __restrict__ g_d2, const float* __restrict__ b_d2,
        u16* __restrict__ y){
    __shared__ float Ag2s[128], Cg2s[128], Ad2s[128], Cd2s[128];
    int t=threadIdx.x;
    {
        int cc=t&127;
        const double* Pp = (t<128)? Pg2 : Pd2;
        const float*  gg = (t<128)? g_g2 : g_d2;
        const float*  bb = (t<128)? b_g2 : b_d2;
        float* Adst = (t<128)? Ag2s : Ad2s;
        float* Cdst = (t<128)? Cg2s : Cd2s;
        affine_reduce(Pp, gg, bb, (double)NKROWS, Adst, Cdst, cc);
    }
    __syncthreads();
    int c=(t&63)*2, h=t>>6;
    int n=blockIdx.x*4+h;
    float sA0=Ag2s[c], sC0=Cg2s[c], pA0=Ad2s[c], pC0=Cd2s[c];
    float sA1=Ag2s[c+1], sC1=Cg2s[c+1], pA1=Ad2s[c+1], pC1=Cd2s[c+1];
    float av0[16], av1[16]; float m0=-1e30f, m1=-1e30f;
#pragma unroll
    for (int k=0;k<16;k++){
        ushort2 tt=*(const ushort2*)(a2+((size_t)n*16+k)*HD+c);
        float a0=h2f(tt.x)*sA0+sC0, a1=h2f(tt.y)*sA1+sC1;
        av0[k]=a0; av1[k]=a1; m0=fmaxf(m0,a0); m1=fmaxf(m1,a1);
    }
    float sum0=0.f, sum1=0.f;
#pragma unroll
    for (int k=0;k<16;k++){
        float e0=__expf(av0[k]-m0), e1=__expf(av1[k]-m1);
        av0[k]=e0; av1[k]=e1; sum0+=e0; sum1+=e1;
    }
    float acc0=0.f, acc1=0.f;
#pragma unroll
    for (int k=0;k<16;k++){
        int g=gidx[n*16+k];
        ushort2 pt=*(const ushort2*)(pose+((size_t)n*16+k)*HD+c);
        ushort2 vt=*(const ushort2*)(vv+(size_t)g*HD+c);
        acc0 += av0[k]*(h2f(pt.x)*pA0+pC0 + h2f(vt.x));
        acc1 += av1[k]*(h2f(pt.y)*pA1+pC1 + h2f(vt.y));
    }
    ushort2 o; o.x=f2h(acc0/sum0); o.y=f2h(acc1/sum1);
    *(ushort2*)(y+(size_t)n*HD+c)=o;
}

// float4-vectorized residual with inline dn-affine; grid NPTS*HD/1024
__global__ __launch_bounds__(256) void residual(const float* __restrict__ ydown,
        const double* __restrict__ Pin, const float* __restrict__ gin, const float* __restrict__ bin,
        const float* __restrict__ fin, float* __restrict__ fout){
    __shared__ float Ash[128], Csh[128];
    int tid=threadIdx.x;
    if (tid<128) affine_reduce(Pin, gin, bin, (double)NPTS, Ash, Csh, tid);
    __syncthreads();
    size_t i=((size_t)blockIdx.x*256+tid)*4; int c=(int)(i&127);
    float4 yv=*(const float4*)(ydown+i);
    float4 fv=*(const float4*)(fin+i);
    float4 o;
    o.x=yv.x*Ash[c]  +Csh[c]  +fv.x;
    o.y=yv.y*Ash[c+1]+Csh[c+1]+fv.y;
    o.z=yv.z*Ash[c+2]+Csh[c+2]+fv.z;
    o.w=yv.w*Ash[c+3]+Csh[c+3]+fv.w;
    *(float4*)(fout+i)=o;
}

// ---------------------------------------------------------------- launch
extern "C" void kernel_launch(void* const* d_in, const int* in_sizes, int n_in,
                              void* d_out, int out_size, void* d_ws, size_t ws_size,
                              hipStream_t stream){
    const int*   coords=(const int*)d_in[0];
    const float* feats=(const float*)d_in[1];
    const float* W_top=(const float*)d_in[2];
    const float* g_top=(const float*)d_in[3];
    const float* bt_top=(const float*)d_in[4];
    const float* W_phi=(const float*)d_in[5];
    const float* W_psi=(const float*)d_in[6];
    const float* W_alp=(const float*)d_in[7];
    const float* W_d1=(const float*)d_in[8];
    const float* b_d1=(const float*)d_in[9];
    const float* g_d1=(const float*)d_in[10];
    const float* bt_d1=(const float*)d_in[11];
    const float* W_d2=(const float*)d_in[12];
    const float* b_d2=(const float*)d_in[13];
    const float* g_d2=(const float*)d_in[14];
    const float* bt_d2=(const float*)d_in[15];
    const float* W_g1=(const float*)d_in[16];
    const float* b_g1=(const float*)d_in[17];
    const float* g_g1=(const float*)d_in[18];
    const float* bt_g1=(const float*)d_in[19];
    const float* W_g2=(const float*)d_in[20];
    const float* b_g2=(const float*)d_in[21];
    const float* g_g2=(const float*)d_in[22];
    const float* bt_g2=(const float*)d_in[23];
    const float* W_dn=(const float*)d_in[24];
    const float* g_dn=(const float*)d_in[25];
    const float* bt_dn=(const float*)d_in[26];

    char* ws=(char*)d_ws;
    size_t off=0;
    auto carve=[&](size_t bytes)->char*{ char* p=ws+off; off=(off+bytes+255)&~(size_t)255; return p; };
    u32*    pc    =(u32*)   carve((size_t)NPTS*4);
    int*    idxg  =(int*)   carve((size_t)NKROWS*4);
    float*  rel   =(float*) carve((size_t)NKROWS*3*4);
    u16*    h16   =(u16*)   carve((size_t)NPTS*HD*2);
    u16*    qb    =(u16*)   carve((size_t)3*NPTS*HD*2);   // q | kpsi | v contiguous
    u16*    kpb   = qb + (size_t)NPTS*HD;
    u16*    vvb   = qb + (size_t)2*NPTS*HD;
    u16*    yb    =(u16*)   carve((size_t)NPTS*HD*2);     // f16 aggregate output
    float*  ydown =(float*) carve((size_t)NPTS*HD*4);
    float*  fbuf  =(float*) carve((size_t)NPTS*HD*4);
    u16*    wt    =(u16*)   carve((size_t)8*2*16384*2);
    char*   stats =         carve((size_t)NREG*NSLOT*256*8 + 256);  // P regions + sM
    double* P     =(double*)stats;
    u64*    sM    =(u64*)(stats + (size_t)NREG*NSLOT*256*8);
    float*  aff   =(float*) carve(4096);                  // d1 affine only
    float *A_d1=aff, *C_d1=aff+256;
    u16*    pose2 =(u16*)   carve((size_t)NKROWS*HD*2);
    u16*    abuf  =(u16*)   carve((size_t)NKROWS*HD*2);
    if (ws_size < off) return;

    // stats region: stage in {0:top,1:d2,2:g1,3:g2,4:dn} x layer
    auto Preg=[&](int stage,int l)->double*{ return P + (size_t)(stage*2+l)*(NSLOT*256); };

    hipMemsetAsync(stats, 0, (size_t)NREG*NSLOT*256*8 + 256, stream);
    pack_coords<<<dim3(NPTS/256),dim3(256),0,stream>>>(coords, pc);
    WPtrs wp{{W_top,W_phi,W_psi,W_alp,W_d2,W_g1,W_g2,W_dn}};
    prep_weights<<<dim3(8*2*16384/256),dim3(256),0,stream>>>(wp, wt);
    knn3<<<dim3(2048),dim3(512),0,stream>>>(pc, idxg, rel, sM);
    finalize_d1<<<dim3(1),dim3(256),0,stream>>>(sM, W_d1, b_d1, g_d1, bt_d1, A_d1, C_d1);

    const float* fin=feats;
    for (int l=0;l<2;l++){
        const u16* wt_top=wt+(0*2+l)*16384; const u16* wt_phi=wt+(1*2+l)*16384;
        const u16* wt_d2 =wt+(4*2+l)*16384; const u16* wt_g1 =wt+(5*2+l)*16384;
        const u16* wt_g2 =wt+(6*2+l)*16384; const u16* wt_dn =wt+(7*2+l)*16384;

        // h16 = f @ W_top (f16 out, stats -> P(top,l))
        gemm128<CompF32,true,false,true,false><<<dim3(NPTS/128),dim3(256),0,stream>>>(
            CompF32{fin}, wt_top, nullptr, h16, Preg(0,l), 0, 0, nullptr, nullptr, nullptr, 0.0);

        // q / kpsi / vv in ONE launch; top-affine computed inline from P(top,l) (packed staging)
        gemm128<CompH16Aff,true,false,false,true><<<dim3(NPTS/128,3),dim3(256),0,stream>>>(
            CompH16Aff{h16}, wt_phi, nullptr, qb, nullptr, 2*16384, (long)NPTS*HD,
            Preg(0,l), g_top+l*128, bt_top+l*128, (double)NPTS);

        // pose2 = relu(BN1(rel@W_d1+b_d1)) @ W_d2 + b_d2 (stats -> P(d2,l))
        gemm128<CompPose1,true,true,true,false><<<dim3(NKROWS/128),dim3(256),0,stream>>>(
            CompPose1{rel, W_d1+l*384, b_d1+l*128, A_d1+l*128, C_d1+l*128}, wt_d2, b_d2+l*128, pose2,
            Preg(1,l), 0, 0, nullptr, nullptr, nullptr, 0.0);

        // a1 = (q - kpsi[g] + BN(pose2)) @ W_g1 + b_g1; d2-affine inline (packed); stats -> P(g1,l)
        gemm128<CompA0,true,true,true,true><<<dim3(NKROWS/128),dim3(256),0,stream>>>(
            CompA0{qb,kpb,pose2,idxg}, wt_g1, b_g1+l*128, abuf, Preg(2,l), 0, 0,
            Preg(1,l), g_d2+l*128, bt_d2+l*128, (double)NKROWS);

        // a2 = relu(BN(a1)) @ W_g2 + b_g2 (in-place); g1-affine inline (packed); stats -> P(g2,l)
        gemm128<CompH16AffRelu,true,true,true,true><<<dim3(NKROWS/128),dim3(256),0,stream>>>(
            CompH16AffRelu{abuf}, wt_g2, b_g2+l*128, abuf, Preg(3,l), 0, 0,
            Preg(2,l), g_g1+l*128, bt_g1+l*128, (double)NKROWS);

        // softmax over K + aggregate; g2- and d2-affines inline; f16 output
        aggregate<<<dim3(NPTS/4),dim3(256),0,stream>>>(abuf, pose2, vvb, idxg,
            Preg(3,l), g_g2+l*128, bt_g2+l*128, Preg(1,l), g_d2+l*128, bt_d2+l*128, yb);

        // y @ W_down (f16 in, pure-copy staging; stats -> P(dn,l)) ; BN+residual with inline dn-affine
        gemm128<CompH16Plain,false,false,true,false><<<dim3(NPTS/128),dim3(256),0,stream>>>(
            CompH16Plain{yb}, wt_dn, nullptr, ydown, Preg(4,l), 0, 0, nullptr, nullptr, nullptr, 0.0);
        residual<<<dim3(NPTS*HD/1024),dim3(256),0,stream>>>(ydown,
            Preg(4,l), g_dn+l*128, bt_dn+l*128, fin, (l==1)?(float*)d_out:fbuf);
        fin=fbuf;
    }
}